// Round 3
// baseline (5412.417 us; speedup 1.0000x reference)
//
#include <hip/hip_runtime.h>
#include <hip/hip_bf16.h>
#include <math.h>

typedef unsigned short u16;
typedef unsigned int u32;

__device__ __forceinline__ float bf2f(u16 u) { return __uint_as_float(((u32)u) << 16); }
__device__ __forceinline__ u16 f2bf(float f) {
  u32 u = __float_as_uint(f);
  u32 r = u + 0x7fffu + ((u >> 16) & 1u);
  return (u16)(r >> 16);
}

// ---------------------------------------------------------------------------
// Kernel 1: LN1 + shifted-window attention + proj + residual.  One block per
// 8x8 window (2048 blocks). fp32 in, fp32 out: x1 = x + attn_out.
// ---------------------------------------------------------------------------
__global__ __launch_bounds__(256) void k_attn(
    const float* __restrict__ x,
    const float* __restrict__ g1, const float* __restrict__ b1,
    const float* __restrict__ qkvw, const float* __restrict__ rpb,
    const float* __restrict__ projw, const float* __restrict__ projb,
    float* __restrict__ out)
{
  __shared__ u16   xnT[192][68];   // LN1 output, transposed [k][token], bf16
  __shared__ float Aq[64][33];     // q, later attn-out (pad 33)
  __shared__ float Bv[64][36];     // k, later v        (pad 36: 16B-aligned rows)
  __shared__ float sc[64][65];     // scores/probs; reused as bf16 proj_w slice
  __shared__ int   regc[64];       // shift-mask region code per token

  const int tid = threadIdx.x;
  const int blk = blockIdx.x;
  const int b  = blk >> 10;
  const int wh = (blk >> 5) & 31;
  const int ww = blk & 31;

  if (tid < 64) {
    int rr = tid >> 3, cc = tid & 7;
    int hh = wh * 8 + rr, vv = ww * 8 + cc;      // shifted-frame coords
    int rh = (hh < 248) ? 0 : ((hh < 252) ? 1 : 2);
    int rw = (vv < 248) ? 0 : ((vv < 252) ? 1 : 2);
    regc[tid] = rh * 3 + rw;
  }

  // ---- LN1 + gather (roll -4 folded into index) ----
  {
    const int t = tid >> 2, l4 = tid & 3;
    const int rr = t >> 3, cc = t & 7;
    const int oh = (wh * 8 + rr + 4) & 255;
    const int ow = (ww * 8 + cc + 4) & 255;
    const float* px = x + (((size_t)b * 65536 + (size_t)oh * 256 + ow) * 192) + l4 * 48;
    float rv[48];
    float s = 0.f, ss = 0.f;
    const float4* p4 = (const float4*)px;
    #pragma unroll
    for (int i = 0; i < 12; ++i) {
      float4 v = p4[i];
      rv[i*4+0] = v.x; rv[i*4+1] = v.y; rv[i*4+2] = v.z; rv[i*4+3] = v.w;
      s += v.x + v.y + v.z + v.w;
      ss += v.x*v.x + v.y*v.y + v.z*v.z + v.w*v.w;
    }
    s += __shfl_xor(s, 1);  s += __shfl_xor(s, 2);
    ss += __shfl_xor(ss, 1); ss += __shfl_xor(ss, 2);
    const float mean = s * (1.f / 192.f);
    const float var  = ss * (1.f / 192.f) - mean * mean;
    const float rstd = rsqrtf(var + 1e-5f);
    const int c0 = l4 * 48;
    #pragma unroll
    for (int i = 0; i < 48; ++i) {
      const int c = c0 + i;
      xnT[c][t] = f2bf((rv[i] - mean) * rstd * g1[c] + b1[c]);
    }
  }
  __syncthreads();

  // persistent proj accumulators: thread (tf, cq) owns x1[tf][cq*48 .. +48)
  const int tf = tid & 63;
  const int cq = tid >> 6;
  float acc48[48];
  #pragma unroll
  for (int m = 0; m < 48; ++m) acc48[m] = projb[cq * 48 + m];

  for (int h = 0; h < 6; ++h) {
    // (a) q (scaled) -> Aq, k -> Bv
    {
      const int sel = tid >> 7;            // 0: q, 1: k
      const int d = tid & 31;
      const int tq = (tid >> 5) & 3;       // token quarter
      const float* w = qkvw + ((size_t)(sel * 192 + h * 32 + d)) * 192;
      float acc[16];
      #pragma unroll
      for (int i = 0; i < 16; ++i) acc[i] = 0.f;
      #pragma unroll 1
      for (int k0 = 0; k0 < 192; k0 += 4) {
        float4 wv = *(const float4*)(w + k0);
        float wk[4] = {wv.x, wv.y, wv.z, wv.w};
        #pragma unroll
        for (int kk = 0; kk < 4; ++kk) {
          const ushort4* xp = (const ushort4*)&xnT[k0 + kk][tq * 16];
          #pragma unroll
          for (int u = 0; u < 4; ++u) {
            ushort4 xv = xp[u];
            acc[u*4+0] += wk[kk] * bf2f(xv.x);
            acc[u*4+1] += wk[kk] * bf2f(xv.y);
            acc[u*4+2] += wk[kk] * bf2f(xv.z);
            acc[u*4+3] += wk[kk] * bf2f(xv.w);
          }
        }
      }
      if (sel == 0) {
        #pragma unroll
        for (int i = 0; i < 16; ++i) Aq[tq*16+i][d] = acc[i] * 0.1767766952966369f;
      } else {
        #pragma unroll
        for (int i = 0; i < 16; ++i) Bv[tq*16+i][d] = acc[i];
      }
    }
    __syncthreads();

    // (b) scores = q.k + bias + mask
    {
      const int i_ = tid & 63;
      const int jq = tid >> 6;
      float a[32];
      #pragma unroll
      for (int d = 0; d < 32; ++d) a[d] = Aq[i_][d];
      const int mi = regc[i_];
      const int ri = i_ >> 3, ci = i_ & 7;
      #pragma unroll 1
      for (int jj = 0; jj < 16; ++jj) {
        const int j = jq * 16 + jj;
        const float4* bp = (const float4*)&Bv[j][0];
        float acc = 0.f;
        #pragma unroll
        for (int u = 0; u < 8; ++u) {
          float4 q4 = bp[u];
          acc += a[u*4+0]*q4.x + a[u*4+1]*q4.y + a[u*4+2]*q4.z + a[u*4+3]*q4.w;
        }
        const int d0 = ri - (j >> 3) + 7;
        const int d1 = ci - (j & 7) + 7;
        const float bias = rpb[(d0 * 15 + d1) * 6 + h];
        const float msk = (regc[j] == mi) ? 0.f : -100.f;
        sc[i_][j] = acc + bias + msk;
      }
    }
    __syncthreads();

    // (c) softmax rows (4 threads / row)
    {
      const int tr = tid >> 2, l = tid & 3;
      float v[16];
      float mx = -3.0e38f;
      #pragma unroll
      for (int m = 0; m < 16; ++m) { v[m] = sc[tr][l * 16 + m]; mx = fmaxf(mx, v[m]); }
      mx = fmaxf(mx, __shfl_xor(mx, 1));
      mx = fmaxf(mx, __shfl_xor(mx, 2));
      float s = 0.f;
      #pragma unroll
      for (int m = 0; m < 16; ++m) { v[m] = __expf(v[m] - mx); s += v[m]; }
      s += __shfl_xor(s, 1);
      s += __shfl_xor(s, 2);
      const float inv = 1.0f / s;
      #pragma unroll
      for (int m = 0; m < 16; ++m) sc[tr][l * 16 + m] = v[m] * inv;
    }
    __syncthreads();

    // (d) v -> Bv (k is dead)
    {
      const int d = tid & 31;
      const int tq = tid >> 5;             // 0..7 (8 tokens each)
      const float* w = qkvw + ((size_t)(384 + h * 32 + d)) * 192;
      float acc[8];
      #pragma unroll
      for (int i = 0; i < 8; ++i) acc[i] = 0.f;
      #pragma unroll 1
      for (int k0 = 0; k0 < 192; k0 += 4) {
        float4 wv = *(const float4*)(w + k0);
        float wk[4] = {wv.x, wv.y, wv.z, wv.w};
        #pragma unroll
        for (int kk = 0; kk < 4; ++kk) {
          const ushort4* xp = (const ushort4*)&xnT[k0 + kk][tq * 8];
          ushort4 x0 = xp[0], x1 = xp[1];
          acc[0] += wk[kk] * bf2f(x0.x);
          acc[1] += wk[kk] * bf2f(x0.y);
          acc[2] += wk[kk] * bf2f(x0.z);
          acc[3] += wk[kk] * bf2f(x0.w);
          acc[4] += wk[kk] * bf2f(x1.x);
          acc[5] += wk[kk] * bf2f(x1.y);
          acc[6] += wk[kk] * bf2f(x1.z);
          acc[7] += wk[kk] * bf2f(x1.w);
        }
      }
      #pragma unroll
      for (int i = 0; i < 8; ++i) Bv[tq * 8 + i][d] = acc[i];
    }
    __syncthreads();

    // (e) out_h = P @ V -> Aq (q is dead)
    {
      const int t_ = tid & 63;
      const int dq = tid >> 6;
      float acc[8];
      #pragma unroll
      for (int i = 0; i < 8; ++i) acc[i] = 0.f;
      #pragma unroll 1
      for (int j = 0; j < 64; ++j) {
        const float p = sc[t_][j];
        const float4* vp = (const float4*)&Bv[j][dq * 8];
        float4 v0 = vp[0], v1 = vp[1];
        acc[0] += p * v0.x; acc[1] += p * v0.y; acc[2] += p * v0.z; acc[3] += p * v0.w;
        acc[4] += p * v1.x; acc[5] += p * v1.y; acc[6] += p * v1.z; acc[7] += p * v1.w;
      }
      #pragma unroll
      for (int i = 0; i < 8; ++i) Aq[t_][dq * 8 + i] = acc[i];
    }
    __syncthreads();

    // (f1) stage proj_w[:, h*32 .. +32) as bf16 into sc region (scores dead)
    {
      u16* wsl = (u16*)&sc[0][0];
      #pragma unroll
      for (int i = 0; i < 6; ++i) {
        const int e = (tid + i * 256) * 4;
        const int c = e >> 5, d = e & 31;
        float4 wv = *(const float4*)(projw + (size_t)c * 192 + h * 32 + d);
        ushort4 o;
        o.x = f2bf(wv.x); o.y = f2bf(wv.y); o.z = f2bf(wv.z); o.w = f2bf(wv.w);
        *(ushort4*)(wsl + e) = o;
      }
    }
    __syncthreads();

    // (f2) incremental projection into registers
    {
      const u16* wsl = (const u16*)&sc[0][0];
      float a[32];
      #pragma unroll
      for (int d = 0; d < 32; ++d) a[d] = Aq[tf][d];
      #pragma unroll 1
      for (int m = 0; m < 48; ++m) {
        const ushort4* wp = (const ushort4*)(wsl + (cq * 48 + m) * 32);
        float acc = acc48[m];
        #pragma unroll
        for (int u = 0; u < 8; ++u) {
          ushort4 wv = wp[u];
          acc += a[u*4+0] * bf2f(wv.x) + a[u*4+1] * bf2f(wv.y)
               + a[u*4+2] * bf2f(wv.z) + a[u*4+3] * bf2f(wv.w);
        }
        acc48[m] = acc;
      }
    }
    __syncthreads();
  }

  // residual + store x1 fp32 (window-reverse + roll +4 == gather bijection)
  {
    const int rr = tf >> 3, cc = tf & 7;
    const int oh = (wh * 8 + rr + 4) & 255;
    const int ow = (ww * 8 + cc + 4) & 255;
    const size_t base = ((size_t)b * 65536 + (size_t)oh * 256 + ow) * 192 + cq * 48;
    const float4* px = (const float4*)(x + base);
    float4* po = (float4*)(out + base);
    #pragma unroll
    for (int i = 0; i < 12; ++i) {
      float4 v = px[i];
      float4 o;
      o.x = acc48[i*4+0] + v.x;
      o.y = acc48[i*4+1] + v.y;
      o.z = acc48[i*4+2] + v.z;
      o.w = acc48[i*4+3] + v.w;
      po[i] = o;
    }
  }
}

// ---------------------------------------------------------------------------
// Kernel 2: LN2 + MLP(GELU) + residual, in-place on d_out (fp32 x1 -> final).
// 16 tokens / block, 8192 blocks. Each (token,channel) owned by one thread.
// ---------------------------------------------------------------------------
__global__ __launch_bounds__(256) void k_mlp(
    const float* __restrict__ g2, const float* __restrict__ b2,
    const float* __restrict__ w1, const float* __restrict__ bm1,
    const float* __restrict__ w2, const float* __restrict__ bm2,
    float* __restrict__ io)
{
  __shared__ float xn2T[192][16];  // LN2 output, transposed [k][token]
  __shared__ float h1T[768][17];   // hidden, transposed [j][token] (pad 17)
  const int tid = threadIdx.x;
  const size_t tok0 = (size_t)blockIdx.x * 16;

  // ---- LN2 (16 threads / token) ----
  {
    const int t = tid >> 4, l = tid & 15;
    const float* px = io + (tok0 + t) * 192 + l * 12;
    float rv[12];
    float s = 0.f, ss = 0.f;
    const float4* p4 = (const float4*)px;
    #pragma unroll
    for (int i = 0; i < 3; ++i) {
      float4 v = p4[i];
      rv[i*4+0] = v.x; rv[i*4+1] = v.y; rv[i*4+2] = v.z; rv[i*4+3] = v.w;
      s += v.x + v.y + v.z + v.w;
      ss += v.x*v.x + v.y*v.y + v.z*v.z + v.w*v.w;
    }
    #pragma unroll
    for (int m = 1; m < 16; m <<= 1) { s += __shfl_xor(s, m); ss += __shfl_xor(ss, m); }
    const float mean = s * (1.f / 192.f);
    const float var  = ss * (1.f / 192.f) - mean * mean;
    const float rstd = rsqrtf(var + 1e-5f);
    #pragma unroll
    for (int i = 0; i < 12; ++i) {
      const int c = l * 12 + i;
      xn2T[c][t] = (rv[i] - mean) * rstd * g2[c] + b2[c];
    }
  }
  __syncthreads();

  // ---- phase 1: h1 = gelu(xn2 @ w1^T + b1); thread owns j = tid,+256,+512 ----
  {
    float acc[3][16];
    #pragma unroll
    for (int jj = 0; jj < 3; ++jj) {
      const float bv = bm1[tid + jj * 256];
      #pragma unroll
      for (int i = 0; i < 16; ++i) acc[jj][i] = bv;
    }
    #pragma unroll 1
    for (int k0 = 0; k0 < 192; k0 += 4) {
      float4 wv0 = *(const float4*)(w1 + (size_t)(tid      ) * 192 + k0);
      float4 wv1 = *(const float4*)(w1 + (size_t)(tid + 256) * 192 + k0);
      float4 wv2 = *(const float4*)(w1 + (size_t)(tid + 512) * 192 + k0);
      const float wk0[4] = {wv0.x, wv0.y, wv0.z, wv0.w};
      const float wk1[4] = {wv1.x, wv1.y, wv1.z, wv1.w};
      const float wk2[4] = {wv2.x, wv2.y, wv2.z, wv2.w};
      #pragma unroll
      for (int kk = 0; kk < 4; ++kk) {
        const float4* xp = (const float4*)&xn2T[k0 + kk][0];
        float4 a0 = xp[0], a1 = xp[1], a2 = xp[2], a3 = xp[3];
        const float wa = wk0[kk], wb = wk1[kk], wc = wk2[kk];
        float xv[16] = {a0.x,a0.y,a0.z,a0.w, a1.x,a1.y,a1.z,a1.w,
                        a2.x,a2.y,a2.z,a2.w, a3.x,a3.y,a3.z,a3.w};
        #pragma unroll
        for (int i = 0; i < 16; ++i) acc[0][i] += wa * xv[i];
        #pragma unroll
        for (int i = 0; i < 16; ++i) acc[1][i] += wb * xv[i];
        #pragma unroll
        for (int i = 0; i < 16; ++i) acc[2][i] += wc * xv[i];
      }
    }
    #pragma unroll
    for (int jj = 0; jj < 3; ++jj) {
      const int j = tid + jj * 256;
      #pragma unroll
      for (int i = 0; i < 16; ++i) {
        const float vv = acc[jj][i];
        h1T[j][i] = 0.5f * vv * (1.f + erff(vv * 0.70710678118654752f));
      }
    }
  }
  __syncthreads();

  // ---- phase 2: out = x1 + h1 @ w2^T + b2; thread owns 3 channels x 4 tokens ----
  {
    const int cb = (tid & 63) * 3;   // 0..189
    const int tq = tid >> 6;         // token quad
    float acc[3][4];
    #pragma unroll
    for (int n = 0; n < 3; ++n) {
      const float bv = bm2[cb + n];
      #pragma unroll
      for (int i = 0; i < 4; ++i) acc[n][i] = bv;
    }
    #pragma unroll 1
    for (int j0 = 0; j0 < 768; j0 += 4) {
      float4 wva = *(const float4*)(w2 + (size_t)(cb + 0) * 768 + j0);
      float4 wvb = *(const float4*)(w2 + (size_t)(cb + 1) * 768 + j0);
      float4 wvc = *(const float4*)(w2 + (size_t)(cb + 2) * 768 + j0);
      const float wk0[4] = {wva.x, wva.y, wva.z, wva.w};
      const float wk1[4] = {wvb.x, wvb.y, wvb.z, wvb.w};
      const float wk2[4] = {wvc.x, wvc.y, wvc.z, wvc.w};
      #pragma unroll
      for (int kk = 0; kk < 4; ++kk) {
        const float* hp = &h1T[j0 + kk][tq * 4];
        float h0 = hp[0], h1v = hp[1], h2 = hp[2], h3 = hp[3];
        const float wa = wk0[kk], wb = wk1[kk], wc = wk2[kk];
        acc[0][0] += wa * h0; acc[0][1] += wa * h1v; acc[0][2] += wa * h2; acc[0][3] += wa * h3;
        acc[1][0] += wb * h0; acc[1][1] += wb * h1v; acc[1][2] += wb * h2; acc[1][3] += wb * h3;
        acc[2][0] += wc * h0; acc[2][1] += wc * h1v; acc[2][2] += wc * h2; acc[2][3] += wc * h3;
      }
    }
    #pragma unroll
    for (int i = 0; i < 4; ++i) {
      float* p = io + (tok0 + tq * 4 + i) * 192;
      #pragma unroll
      for (int n = 0; n < 3; ++n) {
        const int c = cb + n;
        p[c] = acc[n][i] + p[c];   // residual read-then-write, same thread
      }
    }
  }
}

extern "C" void kernel_launch(void* const* d_in, const int* in_sizes, int n_in,
                              void* d_out, int out_size, void* d_ws, size_t ws_size,
                              hipStream_t stream) {
  (void)in_sizes; (void)n_in; (void)out_size; (void)d_ws; (void)ws_size;
  const float* x    = (const float*)d_in[0];
  const float* n1g  = (const float*)d_in[1];
  const float* n1b  = (const float*)d_in[2];
  const float* qkvw = (const float*)d_in[3];
  const float* rpb  = (const float*)d_in[4];
  const float* pw   = (const float*)d_in[5];
  const float* pb   = (const float*)d_in[6];
  const float* n2g  = (const float*)d_in[7];
  const float* n2b  = (const float*)d_in[8];
  const float* w1   = (const float*)d_in[9];
  const float* bm1  = (const float*)d_in[10];
  const float* w2   = (const float*)d_in[11];
  const float* bm2  = (const float*)d_in[12];
  float* out = (float*)d_out;

  hipLaunchKernelGGL(k_attn, dim3(2048), dim3(256), 0, stream,
                     x, n1g, n1b, qkvw, rpb, pw, pb, out);
  hipLaunchKernelGGL(k_mlp, dim3(8192), dim3(256), 0, stream,
                     n2g, n2b, w1, bm1, w2, bm2, out);
}

// Round 4
// 1694.875 us; speedup vs baseline: 3.1934x; 3.1934x over previous
//
#include <hip/hip_runtime.h>
#include <hip/hip_bf16.h>
#include <math.h>

typedef unsigned short u16;
typedef unsigned int u32;
typedef __attribute__((ext_vector_type(8))) short short8;
typedef __attribute__((ext_vector_type(4))) float floatx4;

__device__ __forceinline__ float bf2f(u16 u) { return __uint_as_float(((u32)u) << 16); }
__device__ __forceinline__ u16 f2bf(float f) {
  u32 u = __float_as_uint(f);
  u32 r = u + 0x7fffu + ((u >> 16) & 1u);
  return (u16)(r >> 16);
}

// ---------------------------------------------------------------------------
// Kernel 1: LN1 + shifted-window attention + proj + residual.  One block per
// 8x8 window (2048 blocks). fp32 in, fp32 out: x1 = x + attn_out.
// (unchanged from round 3 — passed)
// ---------------------------------------------------------------------------
__global__ __launch_bounds__(256) void k_attn(
    const float* __restrict__ x,
    const float* __restrict__ g1, const float* __restrict__ b1,
    const float* __restrict__ qkvw, const float* __restrict__ rpb,
    const float* __restrict__ projw, const float* __restrict__ projb,
    float* __restrict__ out)
{
  __shared__ u16   xnT[192][68];   // LN1 output, transposed [k][token], bf16
  __shared__ float Aq[64][33];     // q, later attn-out (pad 33)
  __shared__ float Bv[64][36];     // k, later v        (pad 36: 16B-aligned rows)
  __shared__ float sc[64][65];     // scores/probs; reused as bf16 proj_w slice
  __shared__ int   regc[64];       // shift-mask region code per token

  const int tid = threadIdx.x;
  const int blk = blockIdx.x;
  const int b  = blk >> 10;
  const int wh = (blk >> 5) & 31;
  const int ww = blk & 31;

  if (tid < 64) {
    int rr = tid >> 3, cc = tid & 7;
    int hh = wh * 8 + rr, vv = ww * 8 + cc;      // shifted-frame coords
    int rh = (hh < 248) ? 0 : ((hh < 252) ? 1 : 2);
    int rw = (vv < 248) ? 0 : ((vv < 252) ? 1 : 2);
    regc[tid] = rh * 3 + rw;
  }

  // ---- LN1 + gather (roll -4 folded into index) ----
  {
    const int t = tid >> 2, l4 = tid & 3;
    const int rr = t >> 3, cc = t & 7;
    const int oh = (wh * 8 + rr + 4) & 255;
    const int ow = (ww * 8 + cc + 4) & 255;
    const float* px = x + (((size_t)b * 65536 + (size_t)oh * 256 + ow) * 192) + l4 * 48;
    float rv[48];
    float s = 0.f, ss = 0.f;
    const float4* p4 = (const float4*)px;
    #pragma unroll
    for (int i = 0; i < 12; ++i) {
      float4 v = p4[i];
      rv[i*4+0] = v.x; rv[i*4+1] = v.y; rv[i*4+2] = v.z; rv[i*4+3] = v.w;
      s += v.x + v.y + v.z + v.w;
      ss += v.x*v.x + v.y*v.y + v.z*v.z + v.w*v.w;
    }
    s += __shfl_xor(s, 1);  s += __shfl_xor(s, 2);
    ss += __shfl_xor(ss, 1); ss += __shfl_xor(ss, 2);
    const float mean = s * (1.f / 192.f);
    const float var  = ss * (1.f / 192.f) - mean * mean;
    const float rstd = rsqrtf(var + 1e-5f);
    const int c0 = l4 * 48;
    #pragma unroll
    for (int i = 0; i < 48; ++i) {
      const int c = c0 + i;
      xnT[c][t] = f2bf((rv[i] - mean) * rstd * g1[c] + b1[c]);
    }
  }
  __syncthreads();

  // persistent proj accumulators: thread (tf, cq) owns x1[tf][cq*48 .. +48)
  const int tf = tid & 63;
  const int cq = tid >> 6;
  float acc48[48];
  #pragma unroll
  for (int m = 0; m < 48; ++m) acc48[m] = projb[cq * 48 + m];

  for (int h = 0; h < 6; ++h) {
    // (a) q (scaled) -> Aq, k -> Bv
    {
      const int sel = tid >> 7;            // 0: q, 1: k
      const int d = tid & 31;
      const int tq = (tid >> 5) & 3;       // token quarter
      const float* w = qkvw + ((size_t)(sel * 192 + h * 32 + d)) * 192;
      float acc[16];
      #pragma unroll
      for (int i = 0; i < 16; ++i) acc[i] = 0.f;
      #pragma unroll 1
      for (int k0 = 0; k0 < 192; k0 += 4) {
        float4 wv = *(const float4*)(w + k0);
        float wk[4] = {wv.x, wv.y, wv.z, wv.w};
        #pragma unroll
        for (int kk = 0; kk < 4; ++kk) {
          const ushort4* xp = (const ushort4*)&xnT[k0 + kk][tq * 16];
          #pragma unroll
          for (int u = 0; u < 4; ++u) {
            ushort4 xv = xp[u];
            acc[u*4+0] += wk[kk] * bf2f(xv.x);
            acc[u*4+1] += wk[kk] * bf2f(xv.y);
            acc[u*4+2] += wk[kk] * bf2f(xv.z);
            acc[u*4+3] += wk[kk] * bf2f(xv.w);
          }
        }
      }
      if (sel == 0) {
        #pragma unroll
        for (int i = 0; i < 16; ++i) Aq[tq*16+i][d] = acc[i] * 0.1767766952966369f;
      } else {
        #pragma unroll
        for (int i = 0; i < 16; ++i) Bv[tq*16+i][d] = acc[i];
      }
    }
    __syncthreads();

    // (b) scores = q.k + bias + mask
    {
      const int i_ = tid & 63;
      const int jq = tid >> 6;
      float a[32];
      #pragma unroll
      for (int d = 0; d < 32; ++d) a[d] = Aq[i_][d];
      const int mi = regc[i_];
      const int ri = i_ >> 3, ci = i_ & 7;
      #pragma unroll 1
      for (int jj = 0; jj < 16; ++jj) {
        const int j = jq * 16 + jj;
        const float4* bp = (const float4*)&Bv[j][0];
        float acc = 0.f;
        #pragma unroll
        for (int u = 0; u < 8; ++u) {
          float4 q4 = bp[u];
          acc += a[u*4+0]*q4.x + a[u*4+1]*q4.y + a[u*4+2]*q4.z + a[u*4+3]*q4.w;
        }
        const int d0 = ri - (j >> 3) + 7;
        const int d1 = ci - (j & 7) + 7;
        const float bias = rpb[(d0 * 15 + d1) * 6 + h];
        const float msk = (regc[j] == mi) ? 0.f : -100.f;
        sc[i_][j] = acc + bias + msk;
      }
    }
    __syncthreads();

    // (c) softmax rows (4 threads / row)
    {
      const int tr = tid >> 2, l = tid & 3;
      float v[16];
      float mx = -3.0e38f;
      #pragma unroll
      for (int m = 0; m < 16; ++m) { v[m] = sc[tr][l * 16 + m]; mx = fmaxf(mx, v[m]); }
      mx = fmaxf(mx, __shfl_xor(mx, 1));
      mx = fmaxf(mx, __shfl_xor(mx, 2));
      float s = 0.f;
      #pragma unroll
      for (int m = 0; m < 16; ++m) { v[m] = __expf(v[m] - mx); s += v[m]; }
      s += __shfl_xor(s, 1);
      s += __shfl_xor(s, 2);
      const float inv = 1.0f / s;
      #pragma unroll
      for (int m = 0; m < 16; ++m) sc[tr][l * 16 + m] = v[m] * inv;
    }
    __syncthreads();

    // (d) v -> Bv (k is dead)
    {
      const int d = tid & 31;
      const int tq = tid >> 5;             // 0..7 (8 tokens each)
      const float* w = qkvw + ((size_t)(384 + h * 32 + d)) * 192;
      float acc[8];
      #pragma unroll
      for (int i = 0; i < 8; ++i) acc[i] = 0.f;
      #pragma unroll 1
      for (int k0 = 0; k0 < 192; k0 += 4) {
        float4 wv = *(const float4*)(w + k0);
        float wk[4] = {wv.x, wv.y, wv.z, wv.w};
        #pragma unroll
        for (int kk = 0; kk < 4; ++kk) {
          const ushort4* xp = (const ushort4*)&xnT[k0 + kk][tq * 8];
          ushort4 x0 = xp[0], x1 = xp[1];
          acc[0] += wk[kk] * bf2f(x0.x);
          acc[1] += wk[kk] * bf2f(x0.y);
          acc[2] += wk[kk] * bf2f(x0.z);
          acc[3] += wk[kk] * bf2f(x0.w);
          acc[4] += wk[kk] * bf2f(x1.x);
          acc[5] += wk[kk] * bf2f(x1.y);
          acc[6] += wk[kk] * bf2f(x1.z);
          acc[7] += wk[kk] * bf2f(x1.w);
        }
      }
      #pragma unroll
      for (int i = 0; i < 8; ++i) Bv[tq * 8 + i][d] = acc[i];
    }
    __syncthreads();

    // (e) out_h = P @ V -> Aq (q is dead)
    {
      const int t_ = tid & 63;
      const int dq = tid >> 6;
      float acc[8];
      #pragma unroll
      for (int i = 0; i < 8; ++i) acc[i] = 0.f;
      #pragma unroll 1
      for (int j = 0; j < 64; ++j) {
        const float p = sc[t_][j];
        const float4* vp = (const float4*)&Bv[j][dq * 8];
        float4 v0 = vp[0], v1 = vp[1];
        acc[0] += p * v0.x; acc[1] += p * v0.y; acc[2] += p * v0.z; acc[3] += p * v0.w;
        acc[4] += p * v1.x; acc[5] += p * v1.y; acc[6] += p * v1.z; acc[7] += p * v1.w;
      }
      #pragma unroll
      for (int i = 0; i < 8; ++i) Aq[t_][dq * 8 + i] = acc[i];
    }
    __syncthreads();

    // (f1) stage proj_w[:, h*32 .. +32) as bf16 into sc region (scores dead)
    {
      u16* wsl = (u16*)&sc[0][0];
      #pragma unroll
      for (int i = 0; i < 6; ++i) {
        const int e = (tid + i * 256) * 4;
        const int c = e >> 5, d = e & 31;
        float4 wv = *(const float4*)(projw + (size_t)c * 192 + h * 32 + d);
        ushort4 o;
        o.x = f2bf(wv.x); o.y = f2bf(wv.y); o.z = f2bf(wv.z); o.w = f2bf(wv.w);
        *(ushort4*)(wsl + e) = o;
      }
    }
    __syncthreads();

    // (f2) incremental projection into registers
    {
      const u16* wsl = (const u16*)&sc[0][0];
      float a[32];
      #pragma unroll
      for (int d = 0; d < 32; ++d) a[d] = Aq[tf][d];
      #pragma unroll 1
      for (int m = 0; m < 48; ++m) {
        const ushort4* wp = (const ushort4*)(wsl + (cq * 48 + m) * 32);
        float acc = acc48[m];
        #pragma unroll
        for (int u = 0; u < 8; ++u) {
          ushort4 wv = wp[u];
          acc += a[u*4+0] * bf2f(wv.x) + a[u*4+1] * bf2f(wv.y)
               + a[u*4+2] * bf2f(wv.z) + a[u*4+3] * bf2f(wv.w);
        }
        acc48[m] = acc;
      }
    }
    __syncthreads();
  }

  // residual + store x1 fp32 (window-reverse + roll +4 == gather bijection)
  {
    const int rr = tf >> 3, cc = tf & 7;
    const int oh = (wh * 8 + rr + 4) & 255;
    const int ow = (ww * 8 + cc + 4) & 255;
    const size_t base = ((size_t)b * 65536 + (size_t)oh * 256 + ow) * 192 + cq * 48;
    const float4* px = (const float4*)(x + base);
    float4* po = (float4*)(out + base);
    #pragma unroll
    for (int i = 0; i < 12; ++i) {
      float4 v = px[i];
      float4 o;
      o.x = acc48[i*4+0] + v.x;
      o.y = acc48[i*4+1] + v.y;
      o.z = acc48[i*4+2] + v.z;
      o.w = acc48[i*4+3] + v.w;
      po[i] = o;
    }
  }
}

// ---------------------------------------------------------------------------
// Kernel 2 (MFMA): LN2 + MLP(GELU) + residual, in-place on d_out.
// 64 tokens/block, 2048 blocks, 4 waves. Hidden dim processed in 24 chunks
// of 32 with register-prefetched bf16 weight staging.
//   GEMM1: H[64x32] = xn[64x192] @ w1chunk^T   (mfma 16x16x32 bf16)
//   GELU in C-layout, wave-private LDS transpose to A-layout
//   GEMM2: C2[64x192] += G[64x32] @ w2chunk    (accumulated in registers)
// ---------------------------------------------------------------------------
__global__ __launch_bounds__(256) void k_mlp(
    const float* __restrict__ g2, const float* __restrict__ b2,
    const float* __restrict__ w1, const float* __restrict__ bm1,
    const float* __restrict__ w2, const float* __restrict__ bm2,
    float* __restrict__ io)
{
  __shared__ u16 xn[64][200];      // LN2 out, bf16 [token][ch]   (25600 B)
  __shared__ u16 w1s[32][200];     // w1 chunk  [j_local][k]      (12800 B)
  __shared__ u16 w2s[192][40];     // w2 chunk  [c][j_local]      (15360 B)
  __shared__ u16 gs[4][16][40];    // gelu(H) wave-private transpose (5120 B)

  const int tid = threadIdx.x;
  const size_t tok0 = (size_t)blockIdx.x * 64;

  // ---- LN2 (4 threads / token) -> xn bf16 ----
  {
    const int t = tid >> 2, l4 = tid & 3;
    const float* px = io + (tok0 + t) * 192 + l4 * 48;
    float rv[48];
    float s = 0.f, ss = 0.f;
    const float4* p4 = (const float4*)px;
    #pragma unroll
    for (int i = 0; i < 12; ++i) {
      float4 v = p4[i];
      rv[i*4+0] = v.x; rv[i*4+1] = v.y; rv[i*4+2] = v.z; rv[i*4+3] = v.w;
      s += v.x + v.y + v.z + v.w;
      ss += v.x*v.x + v.y*v.y + v.z*v.z + v.w*v.w;
    }
    s += __shfl_xor(s, 1);  s += __shfl_xor(s, 2);
    ss += __shfl_xor(ss, 1); ss += __shfl_xor(ss, 2);
    const float mean = s * (1.f / 192.f);
    const float var  = ss * (1.f / 192.f) - mean * mean;
    const float rstd = rsqrtf(var + 1e-5f);
    const int c0 = l4 * 48;
    #pragma unroll
    for (int i = 0; i < 12; ++i) {
      ushort4 o;
      o.x = f2bf((rv[i*4+0] - mean) * rstd * g2[c0+i*4+0] + b2[c0+i*4+0]);
      o.y = f2bf((rv[i*4+1] - mean) * rstd * g2[c0+i*4+1] + b2[c0+i*4+1]);
      o.z = f2bf((rv[i*4+2] - mean) * rstd * g2[c0+i*4+2] + b2[c0+i*4+2]);
      o.w = f2bf((rv[i*4+3] - mean) * rstd * g2[c0+i*4+3] + b2[c0+i*4+3]);
      *(ushort4*)&xn[t][c0 + i*4] = o;
    }
  }

  const int w = tid >> 6;          // wave: owns tokens [16w,16w+16)
  const int lane = tid & 63;
  const int m = lane & 15;
  const int q = lane >> 4;

  floatx4 c2acc[12];
  #pragma unroll
  for (int ct = 0; ct < 12; ++ct) c2acc[ct] = (floatx4){0.f, 0.f, 0.f, 0.f};

  float4 pw1[6], pw2[6];
  auto prefetchW = [&](int c0) {
    #pragma unroll
    for (int it = 0; it < 6; ++it) {
      const int i = tid + it * 256;
      pw1[it] = *(const float4*)(w1 + (size_t)(c0 + i / 48) * 192 + (i % 48) * 4);
      pw2[it] = *(const float4*)(w2 + (size_t)(i / 8) * 768 + c0 + (i % 8) * 4);
    }
  };
  auto commitW = [&]() {
    #pragma unroll
    for (int it = 0; it < 6; ++it) {
      const int i = tid + it * 256;
      {
        float4 v = pw1[it];
        ushort4 o; o.x = f2bf(v.x); o.y = f2bf(v.y); o.z = f2bf(v.z); o.w = f2bf(v.w);
        *(ushort4*)&w1s[i / 48][(i % 48) * 4] = o;
      }
      {
        float4 v = pw2[it];
        ushort4 o; o.x = f2bf(v.x); o.y = f2bf(v.y); o.z = f2bf(v.z); o.w = f2bf(v.w);
        *(ushort4*)&w2s[i / 8][(i % 8) * 4] = o;
      }
    }
  };

  prefetchW(0);
  commitW();
  __syncthreads();                 // xn + chunk 0 staged

  for (int ch = 0; ch < 24; ++ch) {
    if (ch + 1 < 24) prefetchW((ch + 1) * 32);

    // GEMM1: H tile 16x32, K=192 (6 ksteps)
    floatx4 h0 = (floatx4){0.f, 0.f, 0.f, 0.f};
    floatx4 h1 = (floatx4){0.f, 0.f, 0.f, 0.f};
    #pragma unroll
    for (int s = 0; s < 6; ++s) {
      short8 a  = *(const short8*)&xn[16 * w + m][32 * s + 8 * q];
      short8 b0 = *(const short8*)&w1s[m][32 * s + 8 * q];
      short8 b1 = *(const short8*)&w1s[16 + m][32 * s + 8 * q];
      h0 = __builtin_amdgcn_mfma_f32_16x16x32_bf16(a, b0, h0, 0, 0, 0);
      h1 = __builtin_amdgcn_mfma_f32_16x16x32_bf16(a, b1, h1, 0, 0, 0);
    }

    // bias + exact GELU, write to wave-private transpose buffer
    const int c0 = ch * 32;
    {
      const float bb0 = bm1[c0 + m];
      const float bb1 = bm1[c0 + 16 + m];
      #pragma unroll
      for (int r = 0; r < 4; ++r) {
        float v0 = h0[r] + bb0;
        float v1 = h1[r] + bb1;
        float g0 = 0.5f * v0 * (1.f + erff(v0 * 0.70710678118654752f));
        float g1 = 0.5f * v1 * (1.f + erff(v1 * 0.70710678118654752f));
        gs[w][q * 4 + r][m] = f2bf(g0);
        gs[w][q * 4 + r][16 + m] = f2bf(g1);
      }
    }

    // GEMM2: C2[16x192] += G[16x32] @ w2chunk[32x192], K=32 (1 kstep)
    {
      short8 ap = *(const short8*)&gs[w][m][8 * q];
      #pragma unroll
      for (int ct = 0; ct < 12; ++ct) {
        short8 bp = *(const short8*)&w2s[ct * 16 + m][8 * q];
        c2acc[ct] = __builtin_amdgcn_mfma_f32_16x16x32_bf16(ap, bp, c2acc[ct], 0, 0, 0);
      }
    }

    __syncthreads();               // all waves done reading chunk ch
    if (ch + 1 < 24) {
      commitW();
      __syncthreads();             // chunk ch+1 staged
    }
  }

  // ---- epilogue: out = x1 + C2 + bias (C/D layout: row=q*4+r, col=ct*16+m) ----
  #pragma unroll
  for (int ct = 0; ct < 12; ++ct) {
    const int c = ct * 16 + m;
    const float bb = bm2[c];
    #pragma unroll
    for (int r = 0; r < 4; ++r) {
      const size_t idx = (tok0 + 16 * w + q * 4 + r) * 192 + c;
      io[idx] = c2acc[ct][r] + bb + io[idx];
    }
  }
}

extern "C" void kernel_launch(void* const* d_in, const int* in_sizes, int n_in,
                              void* d_out, int out_size, void* d_ws, size_t ws_size,
                              hipStream_t stream) {
  (void)in_sizes; (void)n_in; (void)out_size; (void)d_ws; (void)ws_size;
  const float* x    = (const float*)d_in[0];
  const float* n1g  = (const float*)d_in[1];
  const float* n1b  = (const float*)d_in[2];
  const float* qkvw = (const float*)d_in[3];
  const float* rpb  = (const float*)d_in[4];
  const float* pw   = (const float*)d_in[5];
  const float* pb   = (const float*)d_in[6];
  const float* n2g  = (const float*)d_in[7];
  const float* n2b  = (const float*)d_in[8];
  const float* w1   = (const float*)d_in[9];
  const float* bm1  = (const float*)d_in[10];
  const float* w2   = (const float*)d_in[11];
  const float* bm2  = (const float*)d_in[12];
  float* out = (float*)d_out;

  hipLaunchKernelGGL(k_attn, dim3(2048), dim3(256), 0, stream,
                     x, n1g, n1b, qkvw, rpb, pw, pb, out);
  hipLaunchKernelGGL(k_mlp, dim3(2048), dim3(256), 0, stream,
                     n2g, n2b, w1, bm1, w2, bm2, out);
}